// Round 7
// baseline (370.851 us; speedup 1.0000x reference)
//
#include <hip/hip_runtime.h>

// MMD loss, class-compacted. total = concat(source[nsd:], target); rows are
// bucketed by class; only within-class pairwise distances computed.
// Bandwidth: m@D@m = 2n*sum(sq) - 2*||sum x||^2 (absmax 0.0, r1-r6).
// r7: pair tiles moved to MFMA (bf16 32x32x16, one wave per 32x32 tile,
// K=512 -> 32 steps, 8-deep load ring). k_pos+k_gather fused (two-level LDS
// rank, 96 blocks; also emits bf16 copy of compact). Dispatches 8 -> 7.
// bf16 dot error ~0.1 abs on d~1e3, bw~256 -> per-pair dK ~1e-5 << thresh.

#define CMAX 32   // >= CLASS_NUM (31)
#define TCAP 12288
#define RCHUNK 16 // row-chunk parallelism for k_colsum

typedef __attribute__((ext_vector_type(8)))  short  short8;   // 8 bf16 (4 VGPRs)
typedef __attribute__((ext_vector_type(8)))  unsigned short ushort8;
typedef __attribute__((ext_vector_type(16))) float  float16;  // MFMA acc

__device__ inline unsigned short f2bf(float x) {  // fp32 -> bf16 RNE
  unsigned u = __float_as_uint(x);
  return (unsigned short)((u + 0x7FFFu + ((u >> 16) & 1u)) >> 16);
}

// ---- K1: labels + row sq + class counts + ssum ----
__global__ __launch_bounds__(256) void k_prep(
    const float* __restrict__ src, const float* __restrict__ tgt,
    const int* __restrict__ slab, const float* __restrict__ tlabel,
    const int* __restrict__ nsd_p,
    int* __restrict__ lab, float* __restrict__ sq,
    int* cnt, int* srccnt, int* tgtcnt, float* ssum,
    int S_total, int T, int D, int C) {
  int nsd = nsd_p[0];
  int S_use = S_total - nsd;
  int N = S_use + T;
  int lane = threadIdx.x & 63;
  int wid = (blockIdx.x * blockDim.x + threadIdx.x) >> 6;
  int nw = (gridDim.x * blockDim.x) >> 6;
  for (int r = wid; r < N; r += nw) {
    int c;
    const float* row;
    if (r < S_use) {
      c = slab[nsd + r];
      row = src + (size_t)(nsd + r) * D;
    } else {
      int t = r - S_use;
      row = tgt + (size_t)t * D;
      float v = (lane < C) ? tlabel[(size_t)t * C + lane] : -3.4e38f;
      int idx = lane;
      for (int o = 32; o > 0; o >>= 1) {
        float ov = __shfl_down(v, o, 64);
        int oi = __shfl_down(idx, o, 64);
        if (ov > v || (ov == v && oi < idx)) { v = ov; idx = oi; }
      }
      c = __shfl(idx, 0, 64);
    }
    const float4* r4 = (const float4*)row;
    float s = 0.f;
    for (int i = lane; i < (D >> 2); i += 64) {
      float4 q = r4[i];
      s += q.x * q.x + q.y * q.y + q.z * q.z + q.w * q.w;
    }
    for (int o = 32; o > 0; o >>= 1) s += __shfl_down(s, o, 64);
    if (lane == 0) {
      sq[r] = s; lab[r] = c;
      atomicAdd(&cnt[c], 1);
      atomicAdd(&ssum[c], s);
      if (r < S_use) atomicAdd(&srccnt[c], 1); else atomicAdd(&tgtcnt[c], 1);
    }
  }
}

// ---- K2: scan of counts + per-tile lookup table (single block) ----
__global__ __launch_bounds__(256) void k_scan(
    const int* __restrict__ cnt, int* offset, int* alloc, int* misc,
    int* tileinfo, int* tileinfo2, int C) {
  __shared__ int s_tp[CMAX + 1], s_tpr[CMAX], s_off[CMAX], s_n[CMAX];
  int tid = threadIdx.x;
  if (tid == 0) {
    int o = 0, tt = 0;
    for (int c = 0; c < C; c++) {
      int n = cnt[c];
      s_off[c] = o; s_n[c] = n;
      offset[c] = o; alloc[c] = o;
      int tpr = (n + 31) >> 5;
      s_tpr[c] = tpr; s_tp[c] = tt;
      o += n; tt += tpr * (tpr + 1) / 2;
    }
    s_tp[C] = tt;
    misc[0] = tt; misc[1] = o;
  }
  __syncthreads();
  int tt = s_tp[C];
  for (int t = tid; t < tt; t += 256) {
    int c = 0;
    while (t >= s_tp[c + 1]) c++;
    int lt = t - s_tp[c];
    int tpr = s_tpr[c];
    int jt = 0;
    while (lt >= tpr - jt) { lt -= tpr - jt; jt++; }
    int kt = jt + lt;
    tileinfo[t] = c | (jt << 8) | (kt << 16);
    tileinfo2[t] = s_off[c] | (s_n[c] << 16);
  }
}

// ---- K3: positions (two-level LDS rank) + gather fp32 & bf16 copies ----
__global__ __launch_bounds__(256) void k_posgather(
    const float* __restrict__ src, const float* __restrict__ tgt,
    const int* __restrict__ nsd_p, const int* __restrict__ lab,
    const float* __restrict__ sq, int* alloc,
    float* __restrict__ compact, unsigned short* __restrict__ compactb,
    float* __restrict__ sqc, float* __restrict__ sgnc,
    int S_total, int T, int D, int C) {
  __shared__ int hist[CMAX], base[CMAX], rowpos[64], rowc[64], rowrank[64];
  int tid = threadIdx.x;
  int nsd = nsd_p[0];
  int S_use = S_total - nsd;
  int N = S_use + T;
  int r0 = blockIdx.x * 64;
  if (tid < CMAX) hist[tid] = 0;
  __syncthreads();
  if (tid < 64) {
    int r = r0 + tid;
    if (r < N) {
      int c = lab[r];
      rowc[tid] = c;
      rowrank[tid] = atomicAdd(&hist[c], 1);
    }
  }
  __syncthreads();
  if (tid < C && hist[tid] > 0) base[tid] = atomicAdd(&alloc[tid], hist[tid]);
  __syncthreads();
  if (tid < 64) {
    int r = r0 + tid;
    if (r < N) {
      int p = base[rowc[tid]] + rowrank[tid];
      rowpos[tid] = p;
      sqc[p] = sq[r];
      sgnc[p] = (r < S_use) ? 1.f : -1.f;
    }
  }
  __syncthreads();
  int lane = tid & 63;
  for (int rr = tid >> 6; rr < 64; rr += 4) {   // wave per row, 16 rows/wave
    int r = r0 + rr;
    if (r >= N) break;
    int p = rowpos[rr];
    const float* row = (r < S_use) ? src + (size_t)(nsd + r) * D
                                   : tgt + (size_t)(r - S_use) * D;
    const float4* s4 = (const float4*)row;
    float4* d4 = (float4*)(compact + (size_t)p * D);
    float4 v0 = s4[lane * 2], v1 = s4[lane * 2 + 1];
    d4[lane * 2] = v0; d4[lane * 2 + 1] = v1;
    ushort8 h;
    h[0] = f2bf(v0.x); h[1] = f2bf(v0.y); h[2] = f2bf(v0.z); h[3] = f2bf(v0.w);
    h[4] = f2bf(v1.x); h[5] = f2bf(v1.y); h[6] = f2bf(v1.z); h[7] = f2bf(v1.w);
    *(ushort8*)(compactb + (size_t)p * D + lane * 8) = h;
  }
}

// ---- K4: per-class column-sum partials (row-chunk parallel, fp32) ----
__global__ __launch_bounds__(256) void k_colsum(
    const float* __restrict__ compact, const int* __restrict__ cnt,
    const int* __restrict__ offset, float* __restrict__ colsum, int D) {
  int c = blockIdx.x;
  int n = cnt[c], off = offset[c];
  int i0 = (int)(((long long)n * blockIdx.y) / gridDim.y);
  int i1 = (int)(((long long)n * (blockIdx.y + 1)) / gridDim.y);
  int tid = threadIdx.x;
  const float* base = compact + (size_t)off * D;
  for (int col = tid; col < D; col += 256) {
    float s = 0.f;
    for (int i = i0; i < i1; i++) s += base[(size_t)i * D + col];
    if (s != 0.f) atomicAdd(&colsum[(size_t)c * D + col], s);
  }
}

// ---- K5: per-class bandwidth from colsum + ssum ----
__global__ __launch_bounds__(256) void k_bw(
    const float* __restrict__ colsum, const float* __restrict__ ssum,
    const int* __restrict__ cnt, float* __restrict__ bwArr, int D) {
  __shared__ float red[4];
  int c = blockIdx.x;
  int tid = threadIdx.x;
  float acc = 0.f;
  for (int d = tid; d < D; d += 256) {
    float v = colsum[(size_t)c * D + d];
    acc += v * v;
  }
  for (int o = 32; o > 0; o >>= 1) acc += __shfl_down(acc, o, 64);
  if ((tid & 63) == 0) red[tid >> 6] = acc;
  __syncthreads();
  if (tid == 0) {
    float ns = red[0] + red[1] + red[2] + red[3];  // ||sum x||^2
    float nf = (float)cnt[c];
    float S1 = 2.f * nf * ssum[c] - 2.f * ns;      // == m @ Dmat @ m
    float bw = S1 / fmaxf(nf * nf - nf, 1.f);
    bw = (bw > 0.f) ? bw : 1.f;
    bwArr[c] = bw * 0.25f;  // / KERNEL_MUL^(KERNEL_NUM//2)
  }
}

// ---- K6: MFMA pair tiles. One wave per 32x32 tile; bf16 32x32x16;
// A/B frags: lane&31 = row of X, k = (lane>>5)*8 + i (identical gather for
// A and B from row-major X -> any common k-permutation cancels in the dot).
// C/D: col=lane&31, row=(reg&3)+8*(reg>>2)+4*(lane>>5)  [m74/m101]. ----
__global__ __launch_bounds__(256) void k_pairs(
    const unsigned short* __restrict__ compactb, const float* __restrict__ sqc,
    const float* __restrict__ sgnc, const int* __restrict__ tileinfo,
    const int* __restrict__ tileinfo2, const int* __restrict__ misc,
    const float* __restrict__ bwArr, float* losssum, int D) {
  int tileTotal = misc[0];
  int tid = threadIdx.x;
  int lane = tid & 63;
  int l31 = lane & 31;
  int half = lane >> 5;
  int wv = blockIdx.x * 4 + (tid >> 6);
  int nwv = gridDim.x * 4;
  int NS = D >> 4;                       // K-steps of 16 (D=512 -> 32)

  for (int t = wv; t < tileTotal; t += nwv) {
    int info = tileinfo[t];
    int c = info & 255, jt = (info >> 8) & 255, kt = (info >> 16) & 255;
    int info2 = tileinfo2[t];
    int off = info2 & 0xFFFF;
    int n = ((unsigned)info2) >> 16;
    int jbase = jt << 5, kbase = kt << 5;
    float wgt = (jt == kt) ? 1.f : 2.f;

    // rows beyond the class block read neighbor/poison data; masked below.
    const unsigned short* pa = compactb + (size_t)(off + jbase + l31) * D + half * 8;
    const unsigned short* pb = compactb + (size_t)(off + kbase + l31) * D + half * 8;

    short8 a[8], b[8];
    #pragma unroll
    for (int s = 0; s < 8; s++) {
      a[s] = *(const short8*)(pa + s * 16);
      b[s] = *(const short8*)(pb + s * 16);
    }
    float16 acc = {};
    for (int s = 0; s < NS; s++) {
      acc = __builtin_amdgcn_mfma_f32_32x32x16_bf16(a[s & 7], b[s & 7], acc, 0, 0, 0);
      if (s + 8 < NS) {
        a[s & 7] = *(const short8*)(pa + (s + 8) * 16);
        b[s & 7] = *(const short8*)(pb + (s + 8) * 16);
      }
    }

    // epilogue in-register: lane's col n = l31; rows via reg map
    float inv0 = 1.f / bwArr[c];
    float sqk = sqc[off + kbase + l31];
    float sgk = sgnc[off + kbase + l31];
    bool kval = (kbase + l31) < n;
    float sqjv = sqc[off + jbase + l31];   // lane l holds row jbase+l
    float sgjv = sgnc[off + jbase + l31];
    float contrib = 0.f;
    #pragma unroll
    for (int r = 0; r < 16; r++) {
      int m = (r & 3) + 8 * (r >> 2) + 4 * half;
      float sqj = __shfl(sqjv, m, 64);
      float sgj = __shfl(sgjv, m, 64);
      if (kval && (jbase + m) < n) {
        float d = fmaxf(sqj + sqk - 2.f * acc[r], 0.f);
        float s = inv0, kv = 0.f;
        #pragma unroll
        for (int q = 0; q < 5; q++) { kv += __expf(-d * s); s *= 0.5f; }
        contrib += sgj * sgk * kv;
      }
    }
    contrib *= wgt;
    for (int o = 32; o > 0; o >>= 1) contrib += __shfl_down(contrib, o, 64);
    if (lane == 0) atomicAdd(&losssum[c], contrib);
  }
}

// ---- K7: final scalar ----
__global__ __launch_bounds__(64) void k_final(
    const int* __restrict__ cnt, const int* __restrict__ srccnt,
    const int* __restrict__ tgtcnt, const float* __restrict__ losssum,
    float* out, int C) {
  int c = threadIdx.x;
  float loss = 0.f, cv = 0.f;
  if (c < C && srccnt[c] > 0 && tgtcnt[c] > 0) {
    float nf = (float)cnt[c];
    loss = losssum[c] / fmaxf(nf * nf, 1.f);
    cv = 1.f;
  }
  for (int o = 32; o > 0; o >>= 1) {
    loss += __shfl_down(loss, o, 64);
    cv   += __shfl_down(cv, o, 64);
  }
  if (threadIdx.x == 0) out[0] = loss / fmaxf(cv, 1.f);
}

extern "C" void kernel_launch(void* const* d_in, const int* in_sizes, int n_in,
                              void* d_out, int out_size, void* d_ws, size_t ws_size,
                              hipStream_t stream) {
  const float* source = (const float*)d_in[0];
  const float* target = (const float*)d_in[1];
  const int* slab     = (const int*)d_in[2];
  const float* tlabel = (const float*)d_in[3];
  const int* nsd_p    = (const int*)d_in[4];
  float* out = (float*)d_out;

  int S_total = in_sizes[2];
  int D = in_sizes[0] / S_total;   // 512
  int T = in_sizes[1] / D;         // 2048
  int C = in_sizes[3] / T;         // 31
  int NMAX = S_total + T;          // 6144 upper bound; actual N read on device

  // workspace layout (4-byte words); zeroed region first
  float* ws = (float*)d_ws;
  int* cnt      = (int*)ws;               // C
  int* srccnt   = cnt + C;                // C
  int* tgtcnt   = srccnt + C;             // C
  float* losssum = (float*)(tgtcnt + C);  // C
  float* ssum   = losssum + C;            // C
  float* colsum = ssum + C;               // C*D
  int zwords    = 5 * C + C * D;          // all zeroed

  int* offset   = (int*)(colsum + (size_t)C * D);  // C
  int* alloc    = offset + C;             // C
  int* misc     = alloc + C;              // 2
  float* bwArr  = (float*)(misc + 2);     // C
  int* lab      = (int*)(bwArr + C);      // NMAX
  float* sq     = (float*)(lab + NMAX);   // NMAX
  float* sqc    = sq + NMAX;              // NMAX
  float* sgnc   = sqc + NMAX;             // NMAX
  int* tileinfo = (int*)(sgnc + NMAX);    // TCAP
  int* tileinfo2 = tileinfo + TCAP;       // TCAP
  size_t words_used = (size_t)zwords + (3 * C + 2) + 4 * NMAX + 2 * TCAP;
  size_t cw = (words_used + 63) & ~(size_t)63;   // 256B-align compact
  float* compact = ws + cw;               // NMAX * D floats
  unsigned short* compactb = (unsigned short*)(compact + (size_t)NMAX * D);  // NMAX*D bf16

  hipMemsetAsync(d_ws, 0, (size_t)zwords * sizeof(int), stream);

  k_prep<<<768, 256, 0, stream>>>(source, target, slab, tlabel, nsd_p,
                                  lab, sq, cnt, srccnt, tgtcnt, ssum,
                                  S_total, T, D, C);
  k_scan<<<1, 256, 0, stream>>>(cnt, offset, alloc, misc, tileinfo, tileinfo2, C);
  k_posgather<<<NMAX / 64, 256, 0, stream>>>(source, target, nsd_p, lab, sq,
                                             alloc, compact, compactb, sqc, sgnc,
                                             S_total, T, D, C);
  k_colsum<<<dim3(C, RCHUNK), 256, 0, stream>>>(compact, cnt, offset, colsum, D);
  k_bw<<<C, 256, 0, stream>>>(colsum, ssum, cnt, bwArr, D);
  k_pairs<<<128, 256, 0, stream>>>(compactb, sqc, sgnc, tileinfo, tileinfo2,
                                   misc, bwArr, losssum, D);
  k_final<<<1, 64, 0, stream>>>(cnt, srccnt, tgtcnt, losssum, out, C);
}

// Round 8
// 141.257 us; speedup vs baseline: 2.6254x; 2.6254x over previous
//
#include <hip/hip_runtime.h>

// MMD loss, class-compacted. total = concat(source[nsd:], target); rows are
// bucketed by class; only within-class pairwise distances computed.
// Bandwidth: m@D@m = 2n*sum(sq) - 2*||sum x||^2 (absmax 0.0, r1-r7).
// r8: MFMA pair kernel fixed: (a) bf16 stored in MFMA-fragment-major panels
// (coalesced 1KB fragment loads), (b) K-loop fully unrolled at D=512 (r7's
// rolled ring forced vmcnt(0) per step -> 245us). Epilogue/C-layout verified
// correct in r7 (absmax 0.0).

#define CMAX 32   // >= CLASS_NUM (31)
#define TCAP 12288
#define RCHUNK 16 // row-chunk parallelism for k_colsum

typedef __attribute__((ext_vector_type(8)))  short  short8;   // 8 bf16
typedef __attribute__((ext_vector_type(8)))  unsigned short ushort8;
typedef __attribute__((ext_vector_type(16))) float  float16;  // MFMA acc

__device__ inline unsigned short f2bf(float x) {  // fp32 -> bf16 RNE
  unsigned u = __float_as_uint(x);
  return (unsigned short)((u + 0x7FFFu + ((u >> 16) & 1u)) >> 16);
}

// ---- K1: labels + row sq + class counts + ssum ----
__global__ __launch_bounds__(256) void k_prep(
    const float* __restrict__ src, const float* __restrict__ tgt,
    const int* __restrict__ slab, const float* __restrict__ tlabel,
    const int* __restrict__ nsd_p,
    int* __restrict__ lab, float* __restrict__ sq,
    int* cnt, int* srccnt, int* tgtcnt, float* ssum,
    int S_total, int T, int D, int C) {
  int nsd = nsd_p[0];
  int S_use = S_total - nsd;
  int N = S_use + T;
  int lane = threadIdx.x & 63;
  int wid = (blockIdx.x * blockDim.x + threadIdx.x) >> 6;
  int nw = (gridDim.x * blockDim.x) >> 6;
  for (int r = wid; r < N; r += nw) {
    int c;
    const float* row;
    if (r < S_use) {
      c = slab[nsd + r];
      row = src + (size_t)(nsd + r) * D;
    } else {
      int t = r - S_use;
      row = tgt + (size_t)t * D;
      float v = (lane < C) ? tlabel[(size_t)t * C + lane] : -3.4e38f;
      int idx = lane;
      for (int o = 32; o > 0; o >>= 1) {
        float ov = __shfl_down(v, o, 64);
        int oi = __shfl_down(idx, o, 64);
        if (ov > v || (ov == v && oi < idx)) { v = ov; idx = oi; }
      }
      c = __shfl(idx, 0, 64);
    }
    const float4* r4 = (const float4*)row;
    float s = 0.f;
    for (int i = lane; i < (D >> 2); i += 64) {
      float4 q = r4[i];
      s += q.x * q.x + q.y * q.y + q.z * q.z + q.w * q.w;
    }
    for (int o = 32; o > 0; o >>= 1) s += __shfl_down(s, o, 64);
    if (lane == 0) {
      sq[r] = s; lab[r] = c;
      atomicAdd(&cnt[c], 1);
      atomicAdd(&ssum[c], s);
      if (r < S_use) atomicAdd(&srccnt[c], 1); else atomicAdd(&tgtcnt[c], 1);
    }
  }
}

// ---- K2: scan (incl. padded frag offsets) + per-tile lookup table ----
__global__ __launch_bounds__(256) void k_scan(
    const int* __restrict__ cnt, int* offset, int* offpad, int* alloc,
    int* misc, int* tileinfo, int* tileinfo2, int* tileinfo3, int C) {
  __shared__ int s_tp[CMAX + 1], s_tpr[CMAX], s_off[CMAX], s_n[CMAX], s_fb[CMAX];
  int tid = threadIdx.x;
  if (tid == 0) {
    int o = 0, tt = 0, opad = 0;
    for (int c = 0; c < C; c++) {
      int n = cnt[c];
      s_off[c] = o; s_n[c] = n; s_fb[c] = opad;
      offset[c] = o; offpad[c] = opad; alloc[c] = o;
      int tpr = (n + 31) >> 5;
      s_tpr[c] = tpr; s_tp[c] = tt;
      o += n; tt += tpr * (tpr + 1) / 2; opad += tpr * 32;
    }
    s_tp[C] = tt;
    misc[0] = tt; misc[1] = o;
  }
  __syncthreads();
  int tt = s_tp[C];
  for (int t = tid; t < tt; t += 256) {
    int c = 0;
    while (t >= s_tp[c + 1]) c++;
    int lt = t - s_tp[c];
    int tpr = s_tpr[c];
    int jt = 0;
    while (lt >= tpr - jt) { lt -= tpr - jt; jt++; }
    int kt = jt + lt;
    tileinfo[t] = c | (jt << 8) | (kt << 16);
    tileinfo2[t] = s_off[c] | (s_n[c] << 16);
    tileinfo3[t] = s_fb[c];
  }
}

// ---- K3: positions + gather fp32 copy + bf16 MFMA-fragment panels ----
// Fragment layout per class: panels of 32 rows; panel base (fb + (jr&~31))*D
// shorts; within panel, K-step s holds 32rows x 16cols as [hf*32+row][8],
// i.e. chunk m=2s+hf (row cols m*8..m*8+7) at s*512 + (hf*32 + row)*8.
__global__ __launch_bounds__(256) void k_posgather(
    const float* __restrict__ src, const float* __restrict__ tgt,
    const int* __restrict__ nsd_p, const int* __restrict__ lab,
    const float* __restrict__ sq, const int* __restrict__ offset,
    const int* __restrict__ offpad, int* alloc,
    float* __restrict__ compact, unsigned short* __restrict__ fragbuf,
    float* __restrict__ sqc, float* __restrict__ sgnc,
    int S_total, int T, int D, int C) {
  __shared__ int hist[CMAX], base[CMAX], rowpos[64], rowc[64], rowrank[64];
  __shared__ int rowjr[64], rowfb[64];
  int tid = threadIdx.x;
  int nsd = nsd_p[0];
  int S_use = S_total - nsd;
  int N = S_use + T;
  int r0 = blockIdx.x * 64;
  if (tid < CMAX) hist[tid] = 0;
  __syncthreads();
  if (tid < 64) {
    int r = r0 + tid;
    if (r < N) {
      int c = lab[r];
      rowc[tid] = c;
      rowrank[tid] = atomicAdd(&hist[c], 1);
    }
  }
  __syncthreads();
  if (tid < C && hist[tid] > 0) base[tid] = atomicAdd(&alloc[tid], hist[tid]);
  __syncthreads();
  if (tid < 64) {
    int r = r0 + tid;
    if (r < N) {
      int c = rowc[tid];
      int p = base[c] + rowrank[tid];
      rowpos[tid] = p;
      rowjr[tid] = p - offset[c];
      rowfb[tid] = offpad[c];
      sqc[p] = sq[r];
      sgnc[p] = (r < S_use) ? 1.f : -1.f;
    }
  }
  __syncthreads();
  int lane = tid & 63;
  for (int rr = tid >> 6; rr < 64; rr += 4) {   // wave per row
    int r = r0 + rr;
    if (r >= N) break;
    int p = rowpos[rr];
    int jr = rowjr[rr], fb = rowfb[rr];
    const float* row = (r < S_use) ? src + (size_t)(nsd + r) * D
                                   : tgt + (size_t)(r - S_use) * D;
    const float4* s4 = (const float4*)row;
    float4* d4 = (float4*)(compact + (size_t)p * D);
    unsigned short* pb = fragbuf + (size_t)(fb + (jr & ~31)) * D;
    int row32 = jr & 31;
    for (int m = lane; m < (D >> 3); m += 64) {  // chunk m: cols m*8..m*8+7
      float4 v0 = s4[m * 2], v1 = s4[m * 2 + 1];
      d4[m * 2] = v0; d4[m * 2 + 1] = v1;
      ushort8 h;
      h[0] = f2bf(v0.x); h[1] = f2bf(v0.y); h[2] = f2bf(v0.z); h[3] = f2bf(v0.w);
      h[4] = f2bf(v1.x); h[5] = f2bf(v1.y); h[6] = f2bf(v1.z); h[7] = f2bf(v1.w);
      int s = m >> 1, hf = m & 1;
      *(ushort8*)(pb + s * 512 + (hf * 32 + row32) * 8) = h;
    }
  }
}

// ---- K4: per-class column-sum partials (row-chunk parallel, fp32) ----
__global__ __launch_bounds__(256) void k_colsum(
    const float* __restrict__ compact, const int* __restrict__ cnt,
    const int* __restrict__ offset, float* __restrict__ colsum, int D) {
  int c = blockIdx.x;
  int n = cnt[c], off = offset[c];
  int i0 = (int)(((long long)n * blockIdx.y) / gridDim.y);
  int i1 = (int)(((long long)n * (blockIdx.y + 1)) / gridDim.y);
  int tid = threadIdx.x;
  const float* base = compact + (size_t)off * D;
  for (int col = tid; col < D; col += 256) {
    float s = 0.f;
    for (int i = i0; i < i1; i++) s += base[(size_t)i * D + col];
    if (s != 0.f) atomicAdd(&colsum[(size_t)c * D + col], s);
  }
}

// ---- K5: per-class bandwidth from colsum + ssum ----
__global__ __launch_bounds__(256) void k_bw(
    const float* __restrict__ colsum, const float* __restrict__ ssum,
    const int* __restrict__ cnt, float* __restrict__ bwArr, int D) {
  __shared__ float red[4];
  int c = blockIdx.x;
  int tid = threadIdx.x;
  float acc = 0.f;
  for (int d = tid; d < D; d += 256) {
    float v = colsum[(size_t)c * D + d];
    acc += v * v;
  }
  for (int o = 32; o > 0; o >>= 1) acc += __shfl_down(acc, o, 64);
  if ((tid & 63) == 0) red[tid >> 6] = acc;
  __syncthreads();
  if (tid == 0) {
    float ns = red[0] + red[1] + red[2] + red[3];  // ||sum x||^2
    float nf = (float)cnt[c];
    float S1 = 2.f * nf * ssum[c] - 2.f * ns;      // == m @ Dmat @ m
    float bw = S1 / fmaxf(nf * nf - nf, 1.f);
    bw = (bw > 0.f) ? bw : 1.f;
    bwArr[c] = bw * 0.25f;  // / KERNEL_MUL^(KERNEL_NUM//2)
  }
}

// ---- K6: MFMA pair tiles. One wave per 32x32 tile; bf16 32x32x16;
// fragment loads coalesced from panel layout (s*512 + lane*8 shorts = 1KB/inst).
// C/D map: col=lane&31, row=(reg&3)+8*(reg>>2)+4*(lane>>5)  [verified r7]. ----
__global__ __launch_bounds__(256) void k_pairs(
    const unsigned short* __restrict__ fragbuf, const float* __restrict__ sqc,
    const float* __restrict__ sgnc, const int* __restrict__ tileinfo,
    const int* __restrict__ tileinfo2, const int* __restrict__ tileinfo3,
    const int* __restrict__ misc, const float* __restrict__ bwArr,
    float* losssum, int D) {
  int tileTotal = misc[0];
  int tid = threadIdx.x;
  int lane = tid & 63;
  int l31 = lane & 31;
  int half = lane >> 5;
  int wv = blockIdx.x * 4 + (tid >> 6);
  int nwv = gridDim.x * 4;

  for (int t = wv; t < tileTotal; t += nwv) {
    int info = tileinfo[t];
    int c = info & 255, jt = (info >> 8) & 255, kt = (info >> 16) & 255;
    int info2 = tileinfo2[t];
    int off = info2 & 0xFFFF;
    int n = ((unsigned)info2) >> 16;
    int fb = tileinfo3[t];
    int jbase = jt << 5, kbase = kt << 5;
    float wgt = (jt == kt) ? 1.f : 2.f;

    const unsigned short* fa = fragbuf + (size_t)(fb + jbase) * D + lane * 8;
    const unsigned short* fbp = fragbuf + (size_t)(fb + kbase) * D + lane * 8;

    float16 acc = {};
    if (D == 512) {
      #pragma unroll
      for (int s = 0; s < 32; s++) {
        short8 a = *(const short8*)(fa + s * 512);
        short8 b = *(const short8*)(fbp + s * 512);
        acc = __builtin_amdgcn_mfma_f32_32x32x16_bf16(a, b, acc, 0, 0, 0);
      }
    } else {
      for (int s = 0; s < (D >> 4); s++) {
        short8 a = *(const short8*)(fa + s * 512);
        short8 b = *(const short8*)(fbp + s * 512);
        acc = __builtin_amdgcn_mfma_f32_32x32x16_bf16(a, b, acc, 0, 0, 0);
      }
    }

    // epilogue: lane's col = l31; rows via reg map
    float inv0 = 1.f / bwArr[c];
    float sqk = sqc[off + kbase + l31];
    float sgk = sgnc[off + kbase + l31];
    bool kval = (kbase + l31) < n;
    float sqjv = sqc[off + jbase + l31];
    float sgjv = sgnc[off + jbase + l31];
    float contrib = 0.f;
    #pragma unroll
    for (int r = 0; r < 16; r++) {
      int m = (r & 3) + 8 * (r >> 2) + 4 * half;
      float sqj = __shfl(sqjv, m, 64);
      float sgj = __shfl(sgjv, m, 64);
      if (kval && (jbase + m) < n) {
        float d = fmaxf(sqj + sqk - 2.f * acc[r], 0.f);
        float s = inv0, kv = 0.f;
        #pragma unroll
        for (int q = 0; q < 5; q++) { kv += __expf(-d * s); s *= 0.5f; }
        contrib += sgj * sgk * kv;
      }
    }
    contrib *= wgt;
    for (int o = 32; o > 0; o >>= 1) contrib += __shfl_down(contrib, o, 64);
    if (lane == 0) atomicAdd(&losssum[c], contrib);
  }
}

// ---- K7: final scalar ----
__global__ __launch_bounds__(64) void k_final(
    const int* __restrict__ cnt, const int* __restrict__ srccnt,
    const int* __restrict__ tgtcnt, const float* __restrict__ losssum,
    float* out, int C) {
  int c = threadIdx.x;
  float loss = 0.f, cv = 0.f;
  if (c < C && srccnt[c] > 0 && tgtcnt[c] > 0) {
    float nf = (float)cnt[c];
    loss = losssum[c] / fmaxf(nf * nf, 1.f);
    cv = 1.f;
  }
  for (int o = 32; o > 0; o >>= 1) {
    loss += __shfl_down(loss, o, 64);
    cv   += __shfl_down(cv, o, 64);
  }
  if (threadIdx.x == 0) out[0] = loss / fmaxf(cv, 1.f);
}

extern "C" void kernel_launch(void* const* d_in, const int* in_sizes, int n_in,
                              void* d_out, int out_size, void* d_ws, size_t ws_size,
                              hipStream_t stream) {
  const float* source = (const float*)d_in[0];
  const float* target = (const float*)d_in[1];
  const int* slab     = (const int*)d_in[2];
  const float* tlabel = (const float*)d_in[3];
  const int* nsd_p    = (const int*)d_in[4];
  float* out = (float*)d_out;

  int S_total = in_sizes[2];
  int D = in_sizes[0] / S_total;   // 512
  int T = in_sizes[1] / D;         // 2048
  int C = in_sizes[3] / T;         // 31
  int NMAX = S_total + T;          // 6144 upper bound; actual N read on device
  int NMAXP = NMAX + 32 * CMAX;    // padded panel capacity

  // workspace layout (4-byte words); zeroed region first
  float* ws = (float*)d_ws;
  int* cnt      = (int*)ws;               // C
  int* srccnt   = cnt + C;                // C
  int* tgtcnt   = srccnt + C;             // C
  float* losssum = (float*)(tgtcnt + C);  // C
  float* ssum   = losssum + C;            // C
  float* colsum = ssum + C;               // C*D
  int zwords    = 5 * C + C * D;          // all zeroed

  int* offset   = (int*)(colsum + (size_t)C * D);  // C
  int* offpad   = offset + C;             // C
  int* alloc    = offpad + C;             // C
  int* misc     = alloc + C;              // 2
  float* bwArr  = (float*)(misc + 2);     // C
  int* lab      = (int*)(bwArr + C);      // NMAX
  float* sq     = (float*)(lab + NMAX);   // NMAX
  float* sqc    = sq + NMAX;              // NMAX
  float* sgnc   = sqc + NMAX;             // NMAX
  int* tileinfo = (int*)(sgnc + NMAX);    // TCAP
  int* tileinfo2 = tileinfo + TCAP;       // TCAP
  int* tileinfo3 = tileinfo2 + TCAP;      // TCAP
  size_t words_used = (size_t)zwords + (4 * C + 2) + 4 * NMAX + 3 * TCAP;
  size_t cw = (words_used + 63) & ~(size_t)63;   // 256B-align compact
  float* compact = ws + cw;               // NMAX * D floats
  unsigned short* fragbuf = (unsigned short*)(compact + (size_t)NMAX * D);  // NMAXP*D bf16

  hipMemsetAsync(d_ws, 0, (size_t)zwords * sizeof(int), stream);

  k_prep<<<768, 256, 0, stream>>>(source, target, slab, tlabel, nsd_p,
                                  lab, sq, cnt, srccnt, tgtcnt, ssum,
                                  S_total, T, D, C);
  k_scan<<<1, 256, 0, stream>>>(cnt, offset, offpad, alloc, misc,
                                tileinfo, tileinfo2, tileinfo3, C);
  k_posgather<<<NMAX / 64, 256, 0, stream>>>(source, target, nsd_p, lab, sq,
                                             offset, offpad, alloc,
                                             compact, fragbuf, sqc, sgnc,
                                             S_total, T, D, C);
  k_colsum<<<dim3(C, RCHUNK), 256, 0, stream>>>(compact, cnt, offset, colsum, D);
  k_bw<<<C, 256, 0, stream>>>(colsum, ssum, cnt, bwArr, D);
  k_pairs<<<256, 256, 0, stream>>>(fragbuf, sqc, sgnc, tileinfo, tileinfo2,
                                   tileinfo3, misc, bwArr, losssum, D);
  k_final<<<1, 64, 0, stream>>>(cnt, srccnt, tgtcnt, losssum, out, C);
}